// Round 1
// baseline (2871.033 us; speedup 1.0000x reference)
//
#include <hip/hip_runtime.h>
#include <math.h>

// LSTM recurrence, 50 steps. B=2048, T=50, F=256, H=256, gates order i,f,g,o.
// Per-step fused GEMM+gates: z = [x_t | h] @ [W;U] + b, per-block tile
// 32 batch rows x 64 j-cols x 4 gates so the nonlinearity epilogue is
// thread-local. fp32 baseline (no fp32 MFMA on CDNA4).

#define B_  2048
#define T_  50
#define F_  256
#define H_  256
#define BM  32     // batch rows per block
#define BJ  64     // hidden cols (per gate) per block
#define BK  32     // k-tile
#define NTHREADS 256

__device__ __forceinline__ float sigmoid_f(float z) {
    return 1.0f / (1.0f + __expf(-z));
}
__device__ __forceinline__ float tanh_f(float z) {
    // tanh(x) = 2*sigmoid(2x) - 1
    return 2.0f / (1.0f + __expf(-2.0f * z)) - 1.0f;
}

__global__ __launch_bounds__(NTHREADS, 1) void lstm_step(
    const float* __restrict__ x,     // [B,T,F]
    const float* __restrict__ Wm,    // [F,4H]
    const float* __restrict__ Um,    // [H,4H]
    const float* __restrict__ bias,  // [4H]
    const float* __restrict__ h_in,  // [B,H]
    const float* __restrict__ c_in,  // [B,H]
    float* __restrict__ h_out,       // [B,H]
    float* __restrict__ c_out,       // [B,H]
    int t)
{
    __shared__ float As[BM][BK];          // [row][k]  4 KB
    __shared__ float Bs[BK][4 * BJ];      // [k][gate*64 + j] 32 KB

    const int tid = threadIdx.x;
    const int j0  = blockIdx.x * BJ;      // 0,64,128,192 within gate
    const int row0 = blockIdx.y * BM;

    // compute-phase thread mapping: rg = row group (4 rows), jp = j pair
    const int rg = tid >> 5;              // 0..7 -> rows 4*rg..4*rg+3
    const int jp = tid & 31;              // j = j0 + 2*jp + {0,1}

    // staging-A mapping: 32 rows x 8 float4
    const int ar = tid >> 3;              // 0..31 row
    const int ak = (tid & 7) << 2;        // 0,4,..,28 k within tile

    // staging-B mapping: wave w stages k rows w*8..w*8+7; lane covers 4 gate
    // chunks x 16 float4
    const int wv   = tid >> 6;            // 0..3
    const int lane = tid & 63;
    const int bc   = lane >> 4;           // gate chunk 0..3
    const int bq   = (lane & 15) << 2;    // 0..60 step 4

    float acc[4][4][2];                   // [rowsub][gate][jsub]
#pragma unroll
    for (int r = 0; r < 4; ++r)
#pragma unroll
        for (int g = 0; g < 4; ++g) {
            acc[r][g][0] = 0.0f;
            acc[r][g][1] = 0.0f;
        }

    const long xrow_base = (long)row0 * T_ * F_ + (long)t * F_;

    for (int kb = 0; kb < (F_ + H_) / BK; ++kb) {
        const int kg0 = kb * BK;

        // ---- stage A tile: rows row0..row0+31, k = kg0..kg0+31 ----
        {
            const int kglob = kg0 + ak;
            float4 av;
            if (kglob < F_) {
                av = *reinterpret_cast<const float4*>(
                    &x[xrow_base + (long)ar * T_ * F_ + kglob]);
            } else {
                av = *reinterpret_cast<const float4*>(
                    &h_in[(long)(row0 + ar) * H_ + (kglob - F_)]);
            }
            *reinterpret_cast<float4*>(&As[ar][ak]) = av;
        }

        // ---- stage B tile: k rows of [W;U], cols 4 gate chunks of 64 ----
#pragma unroll
        for (int i = 0; i < 8; ++i) {
            const int kl = wv * 8 + i;
            const int kglob = kg0 + kl;
            const float* brow = (kglob < F_) ? (Wm + (long)kglob * (4 * H_))
                                             : (Um + (long)(kglob - F_) * (4 * H_));
            float4 bv = *reinterpret_cast<const float4*>(
                &brow[bc * H_ + j0 + bq]);
            *reinterpret_cast<float4*>(&Bs[kl][bc * BJ + bq]) = bv;
        }

        __syncthreads();

        // ---- compute ----
#pragma unroll 4
        for (int k = 0; k < BK; ++k) {
            float a0 = As[4 * rg + 0][k];
            float a1 = As[4 * rg + 1][k];
            float a2 = As[4 * rg + 2][k];
            float a3 = As[4 * rg + 3][k];
#pragma unroll
            for (int g = 0; g < 4; ++g) {
                float b0 = Bs[k][g * BJ + 2 * jp + 0];
                float b1 = Bs[k][g * BJ + 2 * jp + 1];
                acc[0][g][0] += a0 * b0; acc[0][g][1] += a0 * b1;
                acc[1][g][0] += a1 * b0; acc[1][g][1] += a1 * b1;
                acc[2][g][0] += a2 * b0; acc[2][g][1] += a2 * b1;
                acc[3][g][0] += a3 * b0; acc[3][g][1] += a3 * b1;
            }
        }

        __syncthreads();
    }

    // ---- epilogue: gates + cell update ----
#pragma unroll
    for (int r = 0; r < 4; ++r) {
        const int row = row0 + 4 * rg + r;
#pragma unroll
        for (int jj = 0; jj < 2; ++jj) {
            const int j = j0 + 2 * jp + jj;
            float zi = acc[r][0][jj] + bias[0 * H_ + j];
            float zf = acc[r][1][jj] + bias[1 * H_ + j];
            float zg = acc[r][2][jj] + bias[2 * H_ + j];
            float zo = acc[r][3][jj] + bias[3 * H_ + j];
            float ig = sigmoid_f(zi);
            float fg = sigmoid_f(zf);
            float gg = tanh_f(zg);
            float og = sigmoid_f(zo);
            float c_old = c_in[(long)row * H_ + j];
            float c_new = fg * c_old + ig * gg;
            float h_new = og * tanh_f(c_new);
            c_out[(long)row * H_ + j] = c_new;
            h_out[(long)row * H_ + j] = h_new;
        }
    }
}

extern "C" void kernel_launch(void* const* d_in, const int* in_sizes, int n_in,
                              void* d_out, int out_size, void* d_ws, size_t ws_size,
                              hipStream_t stream) {
    const float* x    = (const float*)d_in[0];
    const float* Wm   = (const float*)d_in[1];
    const float* Um   = (const float*)d_in[2];
    const float* bias = (const float*)d_in[3];
    float* out = (float*)d_out;

    float* hA = (float*)d_ws;
    float* hB = hA + (size_t)B_ * H_;
    float* cw = hB + (size_t)B_ * H_;

    hipMemsetAsync(hA, 0, (size_t)B_ * H_ * sizeof(float), stream);
    hipMemsetAsync(cw, 0, (size_t)B_ * H_ * sizeof(float), stream);

    dim3 grid(H_ / BJ, B_ / BM);   // (4, 64) = 256 blocks
    dim3 block(NTHREADS);

    const float* hin = hA;
    float* hout = hB;
    for (int t = 0; t < T_; ++t) {
        float* ho = (t == T_ - 1) ? out : hout;
        float* co = (t == T_ - 1) ? (out + (size_t)B_ * H_) : cw;
        lstm_step<<<grid, block, 0, stream>>>(x, Wm, Um, bias, hin, cw, ho, co, t);
        const float* tmp = hin;
        hin = (t == T_ - 1) ? hin : hout;   // after last step no swap needed
        hout = (float*)tmp;
        hin = (t == T_ - 1) ? (const float*)ho : hin;  // keep simple; unused after loop
        // (plain ping-pong)
        if (t < T_ - 1) { /* swapped above */ }
    }
}

// Round 2
// 554.345 us; speedup vs baseline: 5.1791x; 5.1791x over previous
//
#include <hip/hip_runtime.h>
#include <math.h>

// LSTM recurrence, 50 steps, bf16 MFMA path.
// z = [x_t | h] @ [W;U] + b per step; per-block tile 32 rows x 64 hidden
// cols x 4 gates (gate quads thread-local in MFMA C-layout).
// Weights pre-packed once into ws as bf16 LDS-image panels with XOR swizzle
// baked in -> B staging is linear global_load_lds (width 16), reads
// bank-conflict-free. A (x fp32->bf16, h bf16) reg-staged with matching
// swizzle. h carried bf16 in ws ping-pong, c fp32 in place.

#define B_   2048
#define T_   50
#define F_   256
#define H_   256
#define BM   32
#define BNH  64          // hidden cols per block
#define BK   64
#define NT   256
#define KTOT 512
#define NITER (KTOT / BK)   // 8

typedef __attribute__((ext_vector_type(8))) short short8;
typedef __attribute__((ext_vector_type(4))) float f32x4;
typedef unsigned short ushort_t;

__device__ __forceinline__ ushort_t f2bf(float f) {
    unsigned u = __float_as_uint(f);
    unsigned r = (u + 0x7FFFu + ((u >> 16) & 1u)) >> 16;
    return (ushort_t)r;
}
__device__ __forceinline__ unsigned pack2bf(float lo, float hi) {
    return (unsigned)f2bf(lo) | ((unsigned)f2bf(hi) << 16);
}
__device__ __forceinline__ float sigmoid_f(float z) { return 1.0f / (1.0f + __expf(-z)); }
__device__ __forceinline__ float tanh_f(float z)    { return 2.0f / (1.0f + __expf(-2.0f * z)) - 1.0f; }

// ---------------- weight pack: fp32 [W;U] -> bf16 LDS-image panels --------
// Layout: bpack[jb][it][c][kqpos][8]  (shorts), c = g*64+h (g=gate, h=hidden
// offset within block), kqpos = chunk ^ (c&7) bakes the read-side XOR swizzle.
__global__ void pack_weights(const float* __restrict__ Wm,
                             const float* __restrict__ Um,
                             ushort_t* __restrict__ bpack) {
    int gid = blockIdx.x * blockDim.x + threadIdx.x;   // 65536 threads
    int klog = gid >> 7;          // 0..511 (k row of [W;U])
    int cgp  = gid & 127;         // col group of 8
    const float* src = (klog < F_) ? (Wm + (size_t)klog * (4 * H_))
                                   : (Um + (size_t)(klog - F_) * (4 * H_));
    float4 v0 = *(const float4*)(src + cgp * 8);
    float4 v1 = *(const float4*)(src + cgp * 8 + 4);
    float vals[8] = {v0.x, v0.y, v0.z, v0.w, v1.x, v1.y, v1.z, v1.w};
    int it    = klog >> 6;
    int chunk = (klog >> 3) & 7;
    int jbyte = klog & 7;
#pragma unroll
    for (int j = 0; j < 8; ++j) {
        int colglob = cgp * 8 + j;
        int g   = colglob >> 8;
        int rem = colglob & 255;
        int jb  = rem >> 6;
        int h   = rem & 63;
        int c   = g * 64 + h;
        int kqpos = chunk ^ (c & 7);
        size_t dst = (size_t)jb * 131072 + (size_t)it * 16384
                   + (size_t)c * 64 + kqpos * 8 + jbyte;
        bpack[dst] = f2bf(vals[j]);
    }
}

// ---------------- per-step fused GEMM + gates ------------------------------
__global__ __launch_bounds__(NT) void lstm_step(
    const float* __restrict__ x,        // [B,T,F] fp32
    const float* __restrict__ bias,     // [4H] fp32
    const ushort_t* __restrict__ bpack, // packed bf16 weights
    const ushort_t* __restrict__ hin,   // [B,H] bf16
    ushort_t* __restrict__ hout,        // [B,H] bf16
    float* __restrict__ cws,            // [B,H] fp32 (in place)
    float* __restrict__ outp,           // [2,B,H] fp32 (last step)
    int t, int is_last)
{
    __shared__ ushort_t As[2][BM * BK];       // 2 x 4 KB
    __shared__ ushort_t Bs[2][4 * BNH * BK];  // 2 x 32 KB

    const int tid  = threadIdx.x;
    const int jb   = blockIdx.x;              // 0..3 hidden col block
    const int row0 = blockIdx.y * BM;
    const int wv   = tid >> 6;                // wave 0..3
    const int lane = tid & 63;
    const int r16  = lane & 15;
    const int q    = lane >> 4;

    // A staging mapping: thread -> (row, 16B k-chunk)
    const int sr = tid >> 3;   // 0..31
    const int sc = tid & 7;    // 0..7

    f32x4 acc[2][4];
#pragma unroll
    for (int m = 0; m < 2; ++m)
#pragma unroll
        for (int g = 0; g < 4; ++g) acc[m][g] = (f32x4){0.f, 0.f, 0.f, 0.f};

    const ushort_t* bsrc = bpack + (size_t)jb * 131072;

    // ---- helpers (inlined) ----
    #define LOAD_A(it_, dst_)                                                  \
        do {                                                                   \
            if ((it_) < 4) {                                                   \
                const float* xp = x + (size_t)(row0 + sr) * (T_ * F_)          \
                                    + (size_t)t * F_ + (it_) * BK + sc * 8;    \
                float4 a_ = *(const float4*)xp;                                \
                float4 b_ = *(const float4*)(xp + 4);                          \
                dst_.x = pack2bf(a_.x, a_.y);                                  \
                dst_.y = pack2bf(a_.z, a_.w);                                  \
                dst_.z = pack2bf(b_.x, b_.y);                                  \
                dst_.w = pack2bf(b_.z, b_.w);                                  \
            } else {                                                           \
                dst_ = *(const uint4*)(hin + (size_t)(row0 + sr) * H_          \
                                       + ((it_) - 4) * BK + sc * 8);           \
            }                                                                  \
        } while (0)

    #define WRITE_A(buf_, src_)                                               \
        *(uint4*)(&As[buf_][sr * BK + ((sc ^ (sr & 7)) * 8)]) = (src_)

    #define STAGE_B(buf_, it_)                                                \
        do {                                                                   \
            const ushort_t* gsrc_ = bsrc + (size_t)(it_) * 16384;              \
            _Pragma("unroll")                                                  \
            for (int sub_ = 0; sub_ < 8; ++sub_) {                             \
                int off_ = sub_ * 2048 + tid * 8;                              \
                __builtin_amdgcn_global_load_lds(                              \
                    (const __attribute__((address_space(1))) void*)(gsrc_ + off_), \
                    (__attribute__((address_space(3))) void*)(&Bs[buf_][off_]),\
                    16, 0, 0);                                                 \
            }                                                                  \
        } while (0)

    #define COMPUTE(buf_)                                                     \
        do {                                                                   \
            const ushort_t* ab_ = &As[buf_][0];                                \
            const ushort_t* bb_ = &Bs[buf_][0];                                \
            _Pragma("unroll")                                                  \
            for (int kh_ = 0; kh_ < 2; ++kh_) {                                \
                int chq_ = kh_ * 4 + q;                                        \
                short8 a0_ = *(const short8*)(ab_ + r16 * BK                   \
                                              + ((chq_ ^ (r16 & 7)) * 8));     \
                short8 a1_ = *(const short8*)(ab_ + (r16 + 16) * BK            \
                                              + ((chq_ ^ (r16 & 7)) * 8));     \
                _Pragma("unroll")                                              \
                for (int g_ = 0; g_ < 4; ++g_) {                               \
                    int c_ = g_ * 64 + wv * 16 + r16;                          \
                    short8 b_ = *(const short8*)(bb_ + c_ * BK                 \
                                                 + ((chq_ ^ (c_ & 7)) * 8));   \
                    acc[0][g_] = __builtin_amdgcn_mfma_f32_16x16x32_bf16(      \
                        a0_, b_, acc[0][g_], 0, 0, 0);                         \
                    acc[1][g_] = __builtin_amdgcn_mfma_f32_16x16x32_bf16(      \
                        a1_, b_, acc[1][g_], 0, 0, 0);                         \
                }                                                              \
            }                                                                  \
        } while (0)

    // ---- pipeline: issue loads for tile t+1 before computing tile t ----
    uint4 aregs;
    LOAD_A(0, aregs);
    STAGE_B(0, 0);
    WRITE_A(0, aregs);
    __syncthreads();

    int cur = 0;
#pragma unroll
    for (int it = 0; it < NITER; ++it) {
        uint4 anext;
        if (it < NITER - 1) {
            LOAD_A(it + 1, anext);
            STAGE_B(cur ^ 1, it + 1);
        }
        COMPUTE(cur);
        if (it < NITER - 1) WRITE_A(cur ^ 1, anext);
        __syncthreads();
        cur ^= 1;
    }

    // ---- epilogue: gates + cell update ----
    const int cg = jb * BNH + wv * 16 + r16;   // hidden col 0..255
    const float bi = bias[0 * H_ + cg];
    const float bf_ = bias[1 * H_ + cg];
    const float bg = bias[2 * H_ + cg];
    const float bo = bias[3 * H_ + cg];

#pragma unroll
    for (int m = 0; m < 2; ++m) {
        const int rowb = row0 + m * 16 + q * 4;
#pragma unroll
        for (int j = 0; j < 4; ++j) {
            const int row = rowb + j;
            float zi = acc[m][0][j] + bi;
            float zf = acc[m][1][j] + bf_;
            float zg = acc[m][2][j] + bg;
            float zo = acc[m][3][j] + bo;
            float ig = sigmoid_f(zi);
            float fg = sigmoid_f(zf);
            float gg = tanh_f(zg);
            float og = sigmoid_f(zo);
            size_t idx = (size_t)row * H_ + cg;
            float c_old = cws[idx];
            float c_new = fg * c_old + ig * gg;
            float h_new = og * tanh_f(c_new);
            cws[idx]  = c_new;
            hout[idx] = f2bf(h_new);
            if (is_last) {
                outp[idx] = h_new;
                outp[(size_t)B_ * H_ + idx] = c_new;
            }
        }
    }
}

extern "C" void kernel_launch(void* const* d_in, const int* in_sizes, int n_in,
                              void* d_out, int out_size, void* d_ws, size_t ws_size,
                              hipStream_t stream) {
    const float* x    = (const float*)d_in[0];
    const float* Wm   = (const float*)d_in[1];
    const float* Um   = (const float*)d_in[2];
    const float* bias = (const float*)d_in[3];
    float* out = (float*)d_out;

    // ws layout: bpack(1MB) | hA(1MB) | hB(1MB) | c(2MB)
    ushort_t* bpack = (ushort_t*)d_ws;
    ushort_t* hA = bpack + 524288;
    ushort_t* hB = hA + 524288;
    float*    cw = (float*)(hB + 524288);

    hipMemsetAsync(hA, 0, (size_t)524288 * 2, stream);
    hipMemsetAsync(cw, 0, (size_t)524288 * 4, stream);
    pack_weights<<<256, 256, 0, stream>>>(Wm, Um, bpack);

    dim3 grid(4, B_ / BM);   // (4, 64) = 256 blocks
    const ushort_t* hin = hA;
    ushort_t* hout = hB;
    for (int t = 0; t < T_; ++t) {
        int last = (t == T_ - 1) ? 1 : 0;
        lstm_step<<<grid, NT, 0, stream>>>(x, bias, bpack, hin, hout, cw, out, t, last);
        ushort_t* tmp = (ushort_t*)hin;
        hin = hout;
        hout = tmp;
    }
}